// Round 1
// baseline (370.485 us; speedup 1.0000x reference)
//
#include <hip/hip_runtime.h>
#include <hip/hip_fp16.h>

// Memory_Attention: r = softmax_L(memory @ qs^T) @ qs ; out = (r, memory)
// B=8 L=4096 D=1024 M=512, fp32 in/out.
//
// Plan (round 1):
//   prep_mem16:      memory fp32 -> fp16 [512][1024]
//   prep_transpose:  qs fp32 [b][l][d] -> qsT fp16 [b][d][l]  (for PV B-frags)
//   flash_main:      fused flash attention, fp16 MFMA 16x16x32.
//                    grid 256 = (b,ls,mt) XCD-swizzled; TM=64, L-chunk=1024, TL=256.
//                    Scores: A=mem16 (global/L1), B=qs fp32->fp16 in-reg. PV: A=P via LDS,
//                    B=qsT (global/L1). LSE-partials to ws.
//   combine:         merge 4 L-split partials (exp(m_s-M) weighted), normalize, write r.
// Fallback (ws too small): naive fp32, correct but slow.

#define B_ 8
#define L_ 4096
#define D_ 1024
#define M_ 512

typedef _Float16 halfT;
typedef _Float16 half8 __attribute__((ext_vector_type(8)));
typedef float f32x4 __attribute__((ext_vector_type(4)));

// ---- ws layout (bytes) ----
#define WS_QST_OFF    0ull
#define WS_QST_SZ     (8ull*1024*4096*2)          // 67,108,864
#define WS_MEM16_OFF  (WS_QST_OFF + WS_QST_SZ)
#define WS_MEM16_SZ   (512ull*1024*2)             // 1,048,576
#define WS_RPART_OFF  (WS_MEM16_OFF + WS_MEM16_SZ)
#define WS_RPART_SZ   (4ull*8*512*1024*4)         // 67,108,864
#define WS_MSTAT_OFF  (WS_RPART_OFF + WS_RPART_SZ)
#define WS_MSTAT_SZ   (4ull*8*512*4)              // 65,536
#define WS_LSTAT_OFF  (WS_MSTAT_OFF + WS_MSTAT_SZ)
#define WS_LSTAT_SZ   (4ull*8*512*4)
#define WS_NEED       (WS_LSTAT_OFF + WS_LSTAT_SZ) // 135,397,376

__device__ __forceinline__ f32x4 fmax4(f32x4 a, f32x4 b) {
  f32x4 r; r[0]=fmaxf(a[0],b[0]); r[1]=fmaxf(a[1],b[1]);
  r[2]=fmaxf(a[2],b[2]); r[3]=fmaxf(a[3],b[3]); return r;
}
__device__ __forceinline__ f32x4 shfl_xor4(f32x4 v, int m) {
  f32x4 r; r[0]=__shfl_xor(v[0],m); r[1]=__shfl_xor(v[1],m);
  r[2]=__shfl_xor(v[2],m); r[3]=__shfl_xor(v[3],m); return r;
}

// ---------------- prep kernels ----------------
__global__ void prep_mem16(const float* __restrict__ mem, halfT* __restrict__ mem16) {
  int i = blockIdx.x*256 + threadIdx.x;   // grid 2048 * 256 = 524288 exact
  mem16[i] = (halfT)mem[i];
}

__global__ void prep_transpose(const float* __restrict__ qs, halfT* __restrict__ qsT) {
  __shared__ halfT tile[64][66];
  int b = blockIdx.z, l0 = blockIdx.x*64, d0 = blockIdx.y*64;
  const float* src = qs + ((size_t)b*L_ + l0)*D_ + d0;
  #pragma unroll
  for (int i = 0; i < 16; ++i) {
    int idx = i*256 + threadIdx.x;
    int r = idx >> 6, c = idx & 63;
    tile[r][c] = (halfT)src[(size_t)r*D_ + c];
  }
  __syncthreads();
  halfT* dst = qsT + ((size_t)b*D_ + d0)*L_ + l0;
  #pragma unroll
  for (int i = 0; i < 16; ++i) {
    int idx = i*256 + threadIdx.x;
    int r = idx >> 6, c = idx & 63;
    dst[(size_t)r*L_ + c] = tile[c][r];
  }
}

// ---------------- main fused kernel ----------------
__launch_bounds__(512, 2)
__global__ void flash_main(const float* __restrict__ qs,
                           const halfT* __restrict__ mem16,
                           const halfT* __restrict__ qsT,
                           float* __restrict__ r_part,
                           float* __restrict__ mstat,
                           float* __restrict__ lstat)
{
  // XCD swizzle: consecutive blockIdx -> XCD round robin (blk%8). Group the 8 m-tiles
  // of one (b,ls) chunk onto one XCD for L2 reuse of the qs chunk.
  int wg  = blockIdx.x;          // 0..255
  int xcd = wg & 7;
  int mt  = (wg >> 3) & 7;
  int ph  = wg >> 6;             // 0..3
  int p   = ph*8 + xcd;          // chunk id 0..31
  int b   = p >> 2;
  int ls  = p & 3;

  int m0    = mt*64;
  int lbase = ls*1024;

  int tid = threadIdx.x;
  int w = tid >> 6, lane = tid & 63, lg = lane >> 4, li = lane & 15;

  __shared__ __attribute__((aligned(16))) halfT P_lds[64][272];  // pad: row stride 544B, 16B aligned, 2-way banks
  __shared__ __attribute__((aligned(16))) float rowmax_ws[8][64];
  __shared__ __attribute__((aligned(16))) float rowsum_ws[8][64];
  __shared__ __attribute__((aligned(16))) float mnew_lds[64];
  __shared__ __attribute__((aligned(16))) float f_lds[64];
  __shared__ __attribute__((aligned(16))) float mrun_lds[64];
  __shared__ __attribute__((aligned(16))) float lrun_lds[64];

  if (tid < 64) { mrun_lds[tid] = -3.0e38f; lrun_lds[tid] = 0.0f; }
  __syncthreads();

  f32x4 acc[4][8];
  #pragma unroll
  for (int i=0;i<4;++i)
    #pragma unroll
    for (int j=0;j<8;++j) acc[i][j] = (f32x4){0.f,0.f,0.f,0.f};

  const halfT* Abase = mem16 + (size_t)(m0 + li)*D_;   // + mf*16*D_ + k

  for (int t = 0; t < 4; ++t) {
    int ltile = lbase + t*256;

    // ---------- scores: S[4mf][2lf], wave cols = w*32 + lf*16 + li ----------
    f32x4 S[4][2];
    #pragma unroll
    for (int i=0;i<4;++i) { S[i][0]=(f32x4){0,0,0,0}; S[i][1]=(f32x4){0,0,0,0}; }
    const float* q0 = qs + ((size_t)b*L_ + (ltile + w*32 + li))*D_;
    #pragma unroll 4
    for (int ks = 0; ks < 32; ++ks) {
      int k = ks*32 + lg*8;
      half8 Af[4];
      #pragma unroll
      for (int mf=0; mf<4; ++mf)
        Af[mf] = *(const half8*)(Abase + (size_t)mf*16*D_ + k);
      #pragma unroll
      for (int lf=0; lf<2; ++lf) {
        const float* qp = q0 + (size_t)lf*16*D_ + k;
        f32x4 x0 = *(const f32x4*)qp;
        f32x4 x1 = *(const f32x4*)(qp + 4);
        half8 Bf;
        Bf[0]=(halfT)x0[0]; Bf[1]=(halfT)x0[1]; Bf[2]=(halfT)x0[2]; Bf[3]=(halfT)x0[3];
        Bf[4]=(halfT)x1[0]; Bf[5]=(halfT)x1[1]; Bf[6]=(halfT)x1[2]; Bf[7]=(halfT)x1[3];
        #pragma unroll
        for (int mf=0; mf<4; ++mf)
          S[mf][lf] = __builtin_amdgcn_mfma_f32_16x16x32_f16(Af[mf], Bf, S[mf][lf], 0,0,0);
      }
    }

    // ---------- wave-partial row max (over the wave's 32 cols) ----------
    #pragma unroll
    for (int mf=0; mf<4; ++mf) {
      f32x4 v = fmax4(S[mf][0], S[mf][1]);
      #pragma unroll
      for (int off=1; off<16; off<<=1) v = fmax4(v, shfl_xor4(v, off));
      if (li == 0) *(f32x4*)&rowmax_ws[w][mf*16 + lg*4] = v;
    }
    __syncthreads();

    if (tid < 64) {
      float mx = rowmax_ws[0][tid];
      #pragma unroll
      for (int s=1;s<8;++s) mx = fmaxf(mx, rowmax_ws[s][tid]);
      float mo = mrun_lds[tid];
      float mn = fmaxf(mo, mx);
      mrun_lds[tid] = mn; mnew_lds[tid] = mn;
      f_lds[tid] = __expf(mo - mn);
    }
    __syncthreads();

    // ---------- P = exp(S - mnew), fp16 -> P_lds ; partial row sums ----------
    #pragma unroll
    for (int mf=0; mf<4; ++mf) {
      f32x4 mn4 = *(const f32x4*)&mnew_lds[mf*16 + lg*4];
      f32x4 sum = (f32x4){0,0,0,0};
      #pragma unroll
      for (int lf=0; lf<2; ++lf) {
        f32x4 pv;
        #pragma unroll
        for (int r=0;r<4;++r) pv[r] = __expf(S[mf][lf][r] - mn4[r]);
        sum += pv;
        int col = w*32 + lf*16 + li;
        #pragma unroll
        for (int r=0;r<4;++r) P_lds[mf*16 + lg*4 + r][col] = (halfT)pv[r];
      }
      #pragma unroll
      for (int off=1; off<16; off<<=1) sum += shfl_xor4(sum, off);
      if (li == 0) *(f32x4*)&rowsum_ws[w][mf*16 + lg*4] = sum;
    }
    __syncthreads();

    if (tid < 64) {
      float ts = 0.f;
      #pragma unroll
      for (int s=0;s<8;++s) ts += rowsum_ws[s][tid];
      lrun_lds[tid] = lrun_lds[tid]*f_lds[tid] + ts;
    }
    // (no barrier needed: lrun only read by these same threads later)

    // ---------- rescale acc, then PV over this tile (K = 256) ----------
    #pragma unroll
    for (int mf=0; mf<4; ++mf) {
      f32x4 f4 = *(const f32x4*)&f_lds[mf*16 + lg*4];
      #pragma unroll
      for (int df=0; df<8; ++df) acc[mf][df] *= f4;
    }
    const halfT* Tbase = qsT + ((size_t)b*D_ + (w*128 + li))*L_ + ltile;
    #pragma unroll 2
    for (int ks=0; ks<8; ++ks) {
      int k = ks*32 + lg*8;
      half8 Pf[4];
      #pragma unroll
      for (int mf=0; mf<4; ++mf)
        Pf[mf] = *(const half8*)&P_lds[mf*16 + li][k];
      half8 Bt[8];
      #pragma unroll
      for (int df=0; df<8; ++df)
        Bt[df] = *(const half8*)(Tbase + (size_t)df*16*L_ + k);
      #pragma unroll
      for (int df=0; df<8; ++df)
        #pragma unroll
        for (int mf=0; mf<4; ++mf)
          acc[mf][df] = __builtin_amdgcn_mfma_f32_16x16x32_f16(Pf[mf], Bt[df], acc[mf][df], 0,0,0);
    }
    // P_lds reuse is protected by the two barriers before the next tile's P writes.
  }

  // ---------- epilogue: unnormalized partials + (m,l) stats ----------
  size_t chunk = (size_t)ls*B_ + b;          // [ls][b]
  #pragma unroll
  for (int mf=0; mf<4; ++mf)
    #pragma unroll
    for (int df=0; df<8; ++df)
      #pragma unroll
      for (int r=0; r<4; ++r) {
        int m = m0 + mf*16 + lg*4 + r;
        int d = w*128 + df*16 + li;
        r_part[(chunk*M_ + m)*D_ + d] = acc[mf][df][r];
      }
  if (tid < 64) {
    mstat[chunk*M_ + m0 + tid] = mrun_lds[tid];
    lstat[chunk*M_ + m0 + tid] = lrun_lds[tid];
  }
}

// ---------------- combine the 4 L-split partials ----------------
__global__ void combine(const float* __restrict__ r_part,
                        const float* __restrict__ mstat,
                        const float* __restrict__ lstat,
                        float* __restrict__ out)
{
  int bm = blockIdx.x;        // 0..4095 = b*512+m
  int tid = threadIdx.x;      // 256
  float ms[4], wsc[4];
  float Mx = -3.0e38f;
  #pragma unroll
  for (int s=0;s<4;++s) { ms[s] = mstat[(size_t)s*4096 + bm]; Mx = fmaxf(Mx, ms[s]); }
  float Z = 0.f;
  #pragma unroll
  for (int s=0;s<4;++s) { wsc[s] = __expf(ms[s] - Mx); Z += wsc[s]*lstat[(size_t)s*4096 + bm]; }
  float inv = 1.f / Z;
  for (int d = tid; d < D_; d += 256) {
    float v = 0.f;
    #pragma unroll
    for (int s=0;s<4;++s) v += wsc[s]*r_part[((size_t)s*4096 + bm)*D_ + d];
    out[(size_t)bm*D_ + d] = v*inv;
  }
}

// ---------------- fallback (no workspace): correct, slow fp32 ----------------
__global__ void fallback_kernel(const float* __restrict__ qs,
                                const float* __restrict__ mem,
                                float* __restrict__ out)
{
  __shared__ float w_lds[4][4096];    // 64 KB
  __shared__ float mem_s[4][1024];    // 16 KB
  __shared__ float redb[256];
  int blk = blockIdx.x;               // 0..1023
  int b = blk >> 7;
  int m0 = (blk & 127)*4;
  int tid = threadIdx.x;

  for (int i = tid; i < 4*1024; i += 256)
    mem_s[i>>10][i&1023] = mem[(size_t)(m0 + (i>>10))*D_ + (i&1023)];
  __syncthreads();

  float mx[4] = {-3e38f,-3e38f,-3e38f,-3e38f};
  for (int l = tid; l < L_; l += 256) {
    const float* qp = qs + ((size_t)b*L_ + l)*D_;
    float dot[4] = {0,0,0,0};
    for (int dd = 0; dd < D_; dd += 4) {
      f32x4 qv = *(const f32x4*)(qp + dd);
      #pragma unroll
      for (int mi=0; mi<4; ++mi)
        dot[mi] += qv[0]*mem_s[mi][dd] + qv[1]*mem_s[mi][dd+1]
                 + qv[2]*mem_s[mi][dd+2] + qv[3]*mem_s[mi][dd+3];
    }
    #pragma unroll
    for (int mi=0; mi<4; ++mi) { w_lds[mi][l] = dot[mi]; mx[mi] = fmaxf(mx[mi], dot[mi]); }
  }
  float Mv[4], Zv[4];
  for (int mi=0; mi<4; ++mi) {
    redb[tid] = mx[mi]; __syncthreads();
    for (int s=128; s>0; s>>=1) { if (tid<s) redb[tid]=fmaxf(redb[tid],redb[tid+s]); __syncthreads(); }
    Mv[mi] = redb[0]; __syncthreads();
  }
  float sm[4] = {0,0,0,0};
  for (int l = tid; l < L_; l += 256)
    #pragma unroll
    for (int mi=0; mi<4; ++mi) {
      float wv = __expf(w_lds[mi][l] - Mv[mi]);
      w_lds[mi][l] = wv; sm[mi] += wv;
    }
  for (int mi=0; mi<4; ++mi) {
    redb[tid] = sm[mi]; __syncthreads();
    for (int s=128; s>0; s>>=1) { if (tid<s) redb[tid]+=redb[tid+s]; __syncthreads(); }
    Zv[mi] = redb[0]; __syncthreads();
  }
  int d0 = tid*4;
  f32x4 a[4];
  #pragma unroll
  for (int mi=0;mi<4;++mi) a[mi] = (f32x4){0,0,0,0};
  for (int l = 0; l < L_; ++l) {
    f32x4 qv = *(const f32x4*)(qs + ((size_t)b*L_ + l)*D_ + d0);
    #pragma unroll
    for (int mi=0; mi<4; ++mi) a[mi] += qv * w_lds[mi][l];
  }
  #pragma unroll
  for (int mi=0; mi<4; ++mi) {
    float invz = 1.f/Zv[mi];
    #pragma unroll
    for (int c=0; c<4; ++c)
      out[((size_t)b*M_ + m0 + mi)*D_ + d0 + c] = a[mi][c]*invz;
  }
}

extern "C" void kernel_launch(void* const* d_in, const int* in_sizes, int n_in,
                              void* d_out, int out_size, void* d_ws, size_t ws_size,
                              hipStream_t stream) {
  const float* qs  = (const float*)d_in[0];
  const float* mem = (const float*)d_in[1];
  float* out = (float*)d_out;

  // tuple output: r [8*512*1024] then memory [512*1024]
  hipMemcpyAsync(out + (size_t)B_*M_*D_, mem, (size_t)M_*D_*sizeof(float),
                 hipMemcpyDeviceToDevice, stream);

  if (ws_size >= (size_t)WS_NEED) {
    halfT* qsT    = (halfT*)((char*)d_ws + WS_QST_OFF);
    halfT* mem16  = (halfT*)((char*)d_ws + WS_MEM16_OFF);
    float* r_part = (float*)((char*)d_ws + WS_RPART_OFF);
    float* mstat  = (float*)((char*)d_ws + WS_MSTAT_OFF);
    float* lstat  = (float*)((char*)d_ws + WS_LSTAT_OFF);

    prep_mem16<<<2048, 256, 0, stream>>>(mem, mem16);
    prep_transpose<<<dim3(64,16,8), 256, 0, stream>>>(qs, qsT);
    flash_main<<<256, 512, 0, stream>>>(qs, mem16, qsT, r_part, mstat, lstat);
    combine<<<4096, 256, 0, stream>>>(r_part, mstat, lstat, out);
  } else {
    fallback_kernel<<<1024, 256, 0, stream>>>(qs, mem, out);
  }
}